// Round 2
// baseline (406.993 us; speedup 1.0000x reference)
//
#include <hip/hip_runtime.h>

// LSTM cell: B=1024, U=2048
//   xh = [x | h]  (1024 x 4096)
//   ifgo = xh @ w (4096 x 8192)  -> bf16 MFMA, fp32 accum, into d_ws
//   gates kernel: i,f,g,o -> h_new, c_new -> d_out = [h, h, c]

#define BDIM   1024
#define UDIM   2048
#define KDIM   4096
#define NDIM   8192

#define BM 128
#define BN 128
#define BK 64

typedef __attribute__((ext_vector_type(4))) float  f32x4;
typedef __attribute__((ext_vector_type(8))) short  short8;

__device__ inline unsigned short f2bf(float f) {
    union { float f; unsigned int u; } v; v.f = f;
    unsigned int u = v.u;
    unsigned int lsb = (u >> 16) & 1;
    u += 0x7fffu + lsb;          // round-to-nearest-even
    return (unsigned short)(u >> 16);
}

// ---------------------------------------------------------------------------
// GEMM: C[1024][8192] = concat(x,h)[1024][4096] @ w[4096][8192]
// 128x128 tile per block, 4 waves (2x2), each wave 64x64 (4x4 frags of 16x16).
// LDS: A as [row 0..127][k 0..63] bf16, XOR-swizzled; B transposed [n][k], same.
// ---------------------------------------------------------------------------
__global__ __launch_bounds__(256, 2)
void lstm_gemm(const float* __restrict__ x, const float* __restrict__ h,
               const float* __restrict__ w, float* __restrict__ ifgo) {
    __shared__ unsigned short As[BM * BK];   // 16 KiB
    __shared__ unsigned short Bs[BN * BK];   // 16 KiB

    const int tid  = threadIdx.x;
    const int lane = tid & 63;
    const int wid  = tid >> 6;       // 0..3
    const int wr   = wid >> 1;       // wave row (0..1)
    const int wc   = wid & 1;        // wave col (0..1)
    const int lrow = lane & 15;      // frag row/col within 16
    const int lk   = lane >> 4;      // 0..3 (k-group)

    const int m0 = blockIdx.y * BM;
    const int n0 = blockIdx.x * BN;

    f32x4 acc[4][4];
#pragma unroll
    for (int i = 0; i < 4; ++i)
#pragma unroll
        for (int j = 0; j < 4; ++j)
            acc[i][j] = (f32x4){0.f, 0.f, 0.f, 0.f};

    char* AsB = (char*)As;
    char* BsB = (char*)Bs;

    for (int k0 = 0; k0 < KDIM; k0 += BK) {
        // ---- stage A: 128 rows x 64 k, fp32 -> bf16 (8 elements/thread/pass)
        const float* asrc = (k0 < UDIM) ? (x + (size_t)m0 * UDIM + k0)
                                        : (h + (size_t)m0 * UDIM + (k0 - UDIM));
#pragma unroll
        for (int p = 0; p < 4; ++p) {
            int e    = p * 256 + tid;
            int arow = e >> 3;              // 0..127
            int k8   = (e & 7) * 8;         // 0,8,..,56
            const float* gp = asrc + (size_t)arow * UDIM + k8;
            f32x4 v0 = *(const f32x4*)(gp);
            f32x4 v1 = *(const f32x4*)(gp + 4);
            short8 s;
            s[0] = (short)f2bf(v0[0]); s[1] = (short)f2bf(v0[1]);
            s[2] = (short)f2bf(v0[2]); s[3] = (short)f2bf(v0[3]);
            s[4] = (short)f2bf(v1[0]); s[5] = (short)f2bf(v1[1]);
            s[6] = (short)f2bf(v1[2]); s[7] = (short)f2bf(v1[3]);
            int baddr = arow * 128 + ((k8 * 2) ^ ((arow & 7) << 4));
            *(short8*)(AsB + baddr) = s;
        }
        // ---- stage B transposed: B_lds[n][k] <- w[k0+k][n0+n]
        // task q: n = q&127, kgrp = q>>7 (8 k's per thread, strided loads,
        // coalesced across lanes along n)
#pragma unroll
        for (int p = 0; p < 4; ++p) {
            int q  = p * 256 + tid;
            int n  = q & 127;
            int kg = q >> 7;                // 0..7
            const float* gp = w + (size_t)(k0 + kg * 8) * NDIM + n0 + n;
            short8 s;
#pragma unroll
            for (int j = 0; j < 8; ++j)
                s[j] = (short)f2bf(gp[(size_t)j * NDIM]);
            int baddr = n * 128 + ((kg * 16) ^ ((n & 7) << 4));
            *(short8*)(BsB + baddr) = s;
        }
        __syncthreads();

        // ---- compute: 2 k-slices of 32, 16 MFMA each
#pragma unroll
        for (int kk = 0; kk < 2; ++kk) {
            short8 af[4], bfr[4];
#pragma unroll
            for (int mi = 0; mi < 4; ++mi) {
                int row   = wr * 64 + mi * 16 + lrow;
                int kbyte = kk * 64 + lk * 16;
                af[mi] = *(const short8*)(AsB + row * 128 + (kbyte ^ ((row & 7) << 4)));
            }
#pragma unroll
            for (int ni = 0; ni < 4; ++ni) {
                int row   = wc * 64 + ni * 16 + lrow;
                int kbyte = kk * 64 + lk * 16;
                bfr[ni] = *(const short8*)(BsB + row * 128 + (kbyte ^ ((row & 7) << 4)));
            }
#pragma unroll
            for (int mi = 0; mi < 4; ++mi)
#pragma unroll
                for (int ni = 0; ni < 4; ++ni)
                    acc[mi][ni] = __builtin_amdgcn_mfma_f32_16x16x32_bf16(
                        af[mi], bfr[ni], acc[mi][ni], 0, 0, 0);
        }
        __syncthreads();
    }

    // ---- epilogue: write ifgo fp32. C/D layout: col = lane&15, row = (lane>>4)*4 + r
#pragma unroll
    for (int mi = 0; mi < 4; ++mi) {
        int grow = m0 + wr * 64 + mi * 16 + lk * 4;
#pragma unroll
        for (int ni = 0; ni < 4; ++ni) {
            int gcol = n0 + wc * 64 + ni * 16 + lrow;
            float* op = ifgo + (size_t)grow * NDIM + gcol;
#pragma unroll
            for (int r = 0; r < 4; ++r)
                op[(size_t)r * NDIM] = acc[mi][ni][r];
        }
    }
}

// ---------------------------------------------------------------------------
// Gates: i,f,o -> sigmoid, g -> tanh; c_new = f*c + i*g; h_new = o*tanh(c_new)
// d_out = [h_new | h_new | c_new], each 1024*2048 fp32
// ---------------------------------------------------------------------------
__global__ __launch_bounds__(256)
void lstm_gates(const float* __restrict__ ifgo, const float* __restrict__ c,
                float* __restrict__ out) {
    const int total4 = (BDIM * UDIM) / 4;   // 524288 float4 tasks
    int idx = blockIdx.x * blockDim.x + threadIdx.x;
    if (idx >= total4) return;
    int m  = idx >> 9;          // / 512   (512 float4 per row of U=2048)
    int u4 = idx & 511;
    const f32x4* base = (const f32x4*)(ifgo + (size_t)m * NDIM);
    f32x4 iv = base[u4];
    f32x4 fv = base[512 + u4];
    f32x4 gv = base[1024 + u4];
    f32x4 ov = base[1536 + u4];
    f32x4 cv = ((const f32x4*)c)[idx];
    f32x4 hn, cn;
#pragma unroll
    for (int r = 0; r < 4; ++r) {
        float ii = 1.f / (1.f + __expf(-iv[r]));
        float ff = 1.f / (1.f + __expf(-fv[r]));
        float oo = 1.f / (1.f + __expf(-ov[r]));
        float gg = tanhf(gv[r]);
        float cc = ff * cv[r] + ii * gg;
        cn[r] = cc;
        hn[r] = oo * tanhf(cc);
    }
    ((f32x4*)out)[idx] = hn;
    ((f32x4*)(out + (size_t)BDIM * UDIM))[idx] = hn;
    ((f32x4*)(out + (size_t)2 * BDIM * UDIM))[idx] = cn;
}

extern "C" void kernel_launch(void* const* d_in, const int* in_sizes, int n_in,
                              void* d_out, int out_size, void* d_ws, size_t ws_size,
                              hipStream_t stream) {
    const float* x = (const float*)d_in[0];
    const float* h = (const float*)d_in[1];
    const float* c = (const float*)d_in[2];
    const float* w = (const float*)d_in[3];
    float* ifgo = (float*)d_ws;             // needs 1024*8192*4 = 32 MiB
    float* out  = (float*)d_out;

    dim3 ggrid(NDIM / BN, BDIM / BM);       // (64, 8)
    lstm_gemm<<<ggrid, 256, 0, stream>>>(x, h, w, ifgo);

    int total4 = (BDIM * UDIM) / 4;
    lstm_gates<<<(total4 + 255) / 256, 256, 0, stream>>>(ifgo, c, out);
}

// Round 3
// 294.420 us; speedup vs baseline: 1.3824x; 1.3824x over previous
//
#include <hip/hip_runtime.h>

// LSTM cell: B=1024, U=2048
//   ifgo = [x|h] @ w  (1024x4096 @ 4096x8192), bf16 MFMA fp32-accum -> d_ws
//   gates kernel: sigmoid/tanh gating -> d_out = [h_new, h_new, c_new]
//
// R2 changes vs R1 baseline (249us GEMM latency-bound, 158us gates tanhf-bound):
//  - gates: fast tanh via __expf (libm tanhf was ~10x the roofline cost)
//  - GEMM: v_cvt_pk_bf16_f32 packed conversion (was ~4 VALU/float f2bf)
//  - GEMM: 2-deep pipeline — regs hold tile t+1, loads for t+2 in flight
//    during compute of t; LDS double-buffered; one barrier per K-step.

#define BDIM   1024
#define UDIM   2048
#define KDIM   4096
#define NDIM   8192

#define BM 128
#define BN 128
#define BK 64
#define NT (KDIM / BK)

typedef __attribute__((ext_vector_type(4))) float        f32x4;
typedef __attribute__((ext_vector_type(8))) short        short8;
typedef __attribute__((ext_vector_type(4))) unsigned int u32x4;

__device__ inline unsigned int cvt_pk_bf16(float lo, float hi) {
    unsigned int r;
    asm("v_cvt_pk_bf16_f32 %0, %1, %2" : "=v"(r) : "v"(lo), "v"(hi));
    return r;
}

// ---------------------------------------------------------------------------
// GEMM: 128x128 tile, 4 waves (2x2), 64x64/wave as 4x4 frags of 16x16x32.
// LDS A [row][k] bf16 + B transposed [n][k] bf16, both XOR-swizzled
// (byte ^= (row&7)<<4). Reg-staged (fp32->bf16 conversion forced in-flight).
// ---------------------------------------------------------------------------
__global__ __launch_bounds__(256, 2)
void lstm_gemm(const float* __restrict__ x, const float* __restrict__ h,
               const float* __restrict__ w, float* __restrict__ ifgo) {
    __shared__ unsigned short As[2][BM * BK];   // 2 x 16 KiB
    __shared__ unsigned short Bs[2][BN * BK];   // 2 x 16 KiB

    const int tid  = threadIdx.x;
    const int lane = tid & 63;
    const int wid  = tid >> 6;
    const int wr   = wid >> 1;
    const int wc   = wid & 1;
    const int lrow = lane & 15;
    const int lk   = lane >> 4;

    const int m0 = blockIdx.y * BM;
    const int n0 = blockIdx.x * BN;

    f32x4 acc[4][4];
#pragma unroll
    for (int i = 0; i < 4; ++i)
#pragma unroll
        for (int j = 0; j < 4; ++j)
            acc[i][j] = (f32x4){0.f, 0.f, 0.f, 0.f};

    // in-flight register staging for one tile (A: 32 floats, B: 32 floats)
    f32x4 av[4][2];
    float bv[4][8];

    auto loadA = [&](int t) {
        int k0 = t * BK;
        const float* src = (k0 < UDIM) ? x + (size_t)m0 * UDIM + k0
                                       : h + (size_t)m0 * UDIM + (k0 - UDIM);
#pragma unroll
        for (int p = 0; p < 4; ++p) {
            int e = p * 256 + tid, arow = e >> 3, k8 = (e & 7) * 8;
            const float* gp = src + (size_t)arow * UDIM + k8;
            av[p][0] = *(const f32x4*)gp;
            av[p][1] = *(const f32x4*)(gp + 4);
        }
    };
    auto loadB = [&](int t) {
        int k0 = t * BK;
#pragma unroll
        for (int p = 0; p < 4; ++p) {
            int q = p * 256 + tid, n = q & 127, kg = q >> 7;
            const float* gp = w + (size_t)(k0 + kg * 8) * NDIM + n0 + n;
#pragma unroll
            for (int j = 0; j < 8; ++j) bv[p][j] = gp[(size_t)j * NDIM];
        }
    };
    auto writeAB = [&](int buf) {
        char* AsB = (char*)As[buf];
        char* BsB = (char*)Bs[buf];
#pragma unroll
        for (int p = 0; p < 4; ++p) {
            int e = p * 256 + tid, arow = e >> 3, k8 = (e & 7) * 8;
            u32x4 u;
            u[0] = cvt_pk_bf16(av[p][0][0], av[p][0][1]);
            u[1] = cvt_pk_bf16(av[p][0][2], av[p][0][3]);
            u[2] = cvt_pk_bf16(av[p][1][0], av[p][1][1]);
            u[3] = cvt_pk_bf16(av[p][1][2], av[p][1][3]);
            *(u32x4*)(AsB + arow * 128 + ((k8 * 2) ^ ((arow & 7) << 4))) = u;
        }
#pragma unroll
        for (int p = 0; p < 4; ++p) {
            int q = p * 256 + tid, n = q & 127, kg = q >> 7;
            u32x4 u;
#pragma unroll
            for (int j = 0; j < 4; ++j)
                u[j] = cvt_pk_bf16(bv[p][2 * j], bv[p][2 * j + 1]);
            *(u32x4*)(BsB + n * 128 + ((kg * 16) ^ ((n & 7) << 4))) = u;
        }
    };
    auto compute = [&](int buf) {
        const char* AsB = (const char*)As[buf];
        const char* BsB = (const char*)Bs[buf];
#pragma unroll
        for (int kk = 0; kk < 2; ++kk) {
            short8 af[4], bfr[4];
#pragma unroll
            for (int mi = 0; mi < 4; ++mi) {
                int row = wr * 64 + mi * 16 + lrow;
                int kb  = kk * 64 + lk * 16;
                af[mi] = *(const short8*)(AsB + row * 128 + (kb ^ ((row & 7) << 4)));
            }
#pragma unroll
            for (int ni = 0; ni < 4; ++ni) {
                int row = wc * 64 + ni * 16 + lrow;
                int kb  = kk * 64 + lk * 16;
                bfr[ni] = *(const short8*)(BsB + row * 128 + (kb ^ ((row & 7) << 4)));
            }
#pragma unroll
            for (int mi = 0; mi < 4; ++mi)
#pragma unroll
                for (int ni = 0; ni < 4; ++ni)
                    acc[mi][ni] = __builtin_amdgcn_mfma_f32_16x16x32_bf16(
                        af[mi], bfr[ni], acc[mi][ni], 0, 0, 0);
        }
    };

    // prologue: tile 0 staged to LDS[0]; tile 1 loads in flight
    loadA(0); loadB(0);
    writeAB(0);
    loadA(1); loadB(1);
    __syncthreads();

    for (int t = 0; t < NT; ++t) {
        int cur = t & 1;
        if (t + 1 < NT) {
            writeAB(cur ^ 1);                       // tile t+1 regs -> LDS
            if (t + 2 < NT) { loadA(t + 2); loadB(t + 2); }  // issue t+2
        }
        compute(cur);                               // tile t from LDS
        __syncthreads();
    }

    // epilogue: C/D layout col=lane&15, row=(lane>>4)*4+r
#pragma unroll
    for (int mi = 0; mi < 4; ++mi) {
        int grow = m0 + wr * 64 + mi * 16 + lk * 4;
#pragma unroll
        for (int ni = 0; ni < 4; ++ni) {
            int gcol = n0 + wc * 64 + ni * 16 + lrow;
            float* op = ifgo + (size_t)grow * NDIM + gcol;
#pragma unroll
            for (int r = 0; r < 4; ++r)
                op[(size_t)r * NDIM] = acc[mi][ni][r];
        }
    }
}

// ---------------------------------------------------------------------------
// Gates. tanhf (libm) was ~10x roofline -> fast tanh via __expf:
//   tanh(x) = sign(x) * (1 - e^{-2|x|}) / (1 + e^{-2|x|})
// ---------------------------------------------------------------------------
__device__ inline float fast_sigmoid(float v) {
    return __builtin_amdgcn_rcpf(1.f + __expf(-v));
}
__device__ inline float fast_tanh(float v) {
    float t = __expf(-2.f * __builtin_fabsf(v));
    float r = (1.f - t) * __builtin_amdgcn_rcpf(1.f + t);
    return __builtin_copysignf(r, v);
}

__global__ __launch_bounds__(256)
void lstm_gates(const float* __restrict__ ifgo, const float* __restrict__ c,
                float* __restrict__ out) {
    const int total4 = (BDIM * UDIM) / 4;
    int idx = blockIdx.x * blockDim.x + threadIdx.x;
    if (idx >= total4) return;
    int m  = idx >> 9;
    int u4 = idx & 511;
    const f32x4* base = (const f32x4*)(ifgo + (size_t)m * NDIM);
    f32x4 iv = base[u4];
    f32x4 fv = base[512 + u4];
    f32x4 gv = base[1024 + u4];
    f32x4 ov = base[1536 + u4];
    f32x4 cv = ((const f32x4*)c)[idx];
    f32x4 hn, cn;
#pragma unroll
    for (int r = 0; r < 4; ++r) {
        float ii = fast_sigmoid(iv[r]);
        float ff = fast_sigmoid(fv[r]);
        float oo = fast_sigmoid(ov[r]);
        float gg = fast_tanh(gv[r]);
        float cc = ff * cv[r] + ii * gg;
        cn[r] = cc;
        hn[r] = oo * fast_tanh(cc);
    }
    ((f32x4*)out)[idx] = hn;
    ((f32x4*)(out + (size_t)BDIM * UDIM))[idx] = hn;
    ((f32x4*)(out + (size_t)2 * BDIM * UDIM))[idx] = cn;
}

extern "C" void kernel_launch(void* const* d_in, const int* in_sizes, int n_in,
                              void* d_out, int out_size, void* d_ws, size_t ws_size,
                              hipStream_t stream) {
    const float* x = (const float*)d_in[0];
    const float* h = (const float*)d_in[1];
    const float* c = (const float*)d_in[2];
    const float* w = (const float*)d_in[3];
    float* ifgo = (float*)d_ws;             // 1024*8192*4 = 32 MiB
    float* out  = (float*)d_out;

    dim3 ggrid(NDIM / BN, BDIM / BM);       // (64, 8)
    lstm_gemm<<<ggrid, 256, 0, stream>>>(x, h, w, ifgo);

    int total4 = (BDIM * UDIM) / 4;
    lstm_gates<<<(total4 + 255) / 256, 256, 0, stream>>>(ifgo, c, out);
}